// Round 1
// baseline (292.199 us; speedup 1.0000x reference)
//
#include <hip/hip_runtime.h>
#include <hip/hip_bf16.h>

// Sparse conv gather->GEMM->scatter for MI355X (gfx950).
// features: [N,64] f32, kernel: [27,64,64] f32, neighbor_in/out: [27,L] i32.
// out: [N,64] f32, out[no[k,l], :] += feat[ni[k,l], :] @ W[k]

typedef __bf16 bf16x8 __attribute__((ext_vector_type(8)));
typedef float f32x4 __attribute__((ext_vector_type(4)));

#define KOFF 27

template <int ITER>
__global__ __launch_bounds__(256) void spconv_mfma_kernel(
    const float* __restrict__ feat, const float* __restrict__ kern,
    const int* __restrict__ nin, const int* __restrict__ nout,
    float* __restrict__ out, int Lpairs, int blocksPerK) {
  // Per-block: fixed offset k. Stage W[k] (64x64 f32) as transposed bf16 in LDS.
  __shared__ __bf16 ldsBT[64 * 64];  // ldsBT[c][i] = W[i][c], 8 KB

  const int bk = blockIdx.x / blocksPerK;      // offset index 0..26
  const int chunk = blockIdx.x % blocksPerK;   // pair-chunk within offset

  const float* kb = kern + bk * 4096;
  for (int idx = threadIdx.x; idx < 4096; idx += 256) {
    int i = idx >> 6;      // input channel
    int c = idx & 63;      // output channel
    ldsBT[c * 64 + i] = (__bf16)kb[idx];
  }
  __syncthreads();

  const int lane = threadIdx.x & 63;
  const int wave = threadIdx.x >> 6;
  const int r = lane & 15;   // row-in-16 for A / col-in-16 for B,C
  const int g = lane >> 4;   // lane group 0..3

  // B fragments: bfrag[kstep][ntile], lane holds B[g*8+j + 32*kstep][t*16+r]
  bf16x8 bfrag[2][4];
#pragma unroll
  for (int s = 0; s < 2; ++s)
#pragma unroll
    for (int t = 0; t < 4; ++t)
      bfrag[s][t] = *(const bf16x8*)&ldsBT[(t * 16 + r) * 64 + g * 8 + s * 32];

  const int* ninK = nin + bk * Lpairs;
  const int* noutK = nout + bk * Lpairs;

  const int base0 = chunk * (4 * ITER * 16) + wave * (ITER * 16);

  for (int it = 0; it < ITER; ++it) {
    const int base = base0 + it * 16;
    if (base >= Lpairs) break;  // Lpairs % 16 == 0 -> full tiles only

    // A fragment gather: lane handles pair-row (base + r), channels g*8..g*8+7 (+32)
    const int arow = ninK[base + r];
    const float* ap = feat + (size_t)arow * 64 + g * 8;
    f32x4 f0 = *(const f32x4*)(ap);
    f32x4 f1 = *(const f32x4*)(ap + 4);
    f32x4 f2 = *(const f32x4*)(ap + 32);
    f32x4 f3 = *(const f32x4*)(ap + 36);
    bf16x8 a0, a1;
#pragma unroll
    for (int j = 0; j < 4; ++j) {
      a0[j] = (__bf16)f0[j];
      a0[j + 4] = (__bf16)f1[j];
      a1[j] = (__bf16)f2[j];
      a1[j + 4] = (__bf16)f3[j];
    }

    f32x4 acc[4] = {f32x4{0.f, 0.f, 0.f, 0.f}, f32x4{0.f, 0.f, 0.f, 0.f},
                    f32x4{0.f, 0.f, 0.f, 0.f}, f32x4{0.f, 0.f, 0.f, 0.f}};
#pragma unroll
    for (int t = 0; t < 4; ++t) {
      acc[t] = __builtin_amdgcn_mfma_f32_16x16x32_bf16(a0, bfrag[0][t], acc[t], 0, 0, 0);
      acc[t] = __builtin_amdgcn_mfma_f32_16x16x32_bf16(a1, bfrag[1][t], acc[t], 0, 0, 0);
    }

    // Scatter-add: C/D layout col=lane&15, row=(lane>>4)*4+reg  [measured m89/m91]
    int orow[4];
#pragma unroll
    for (int reg = 0; reg < 4; ++reg) orow[reg] = noutK[base + g * 4 + reg];
#pragma unroll
    for (int t = 0; t < 4; ++t)
#pragma unroll
      for (int reg = 0; reg < 4; ++reg)
        atomicAdd(out + (size_t)orow[reg] * 64 + t * 16 + r, acc[t][reg]);
  }
}

extern "C" void kernel_launch(void* const* d_in, const int* in_sizes, int n_in,
                              void* d_out, int out_size, void* d_ws, size_t ws_size,
                              hipStream_t stream) {
  const float* feat = (const float*)d_in[0];
  const float* kern = (const float*)d_in[1];
  const int* nin = (const int*)d_in[2];
  const int* nout = (const int*)d_in[3];
  float* out = (float*)d_out;

  const int Lpairs = in_sizes[2] / KOFF;  // 50000

  // Zero the (poisoned) output before scatter-add.
  hipMemsetAsync(d_out, 0, (size_t)out_size * sizeof(float), stream);

  constexpr int ITER = 8;
  const int pairsPerBlock = 4 * ITER * 16;  // 512
  const int blocksPerK = (Lpairs + pairsPerBlock - 1) / pairsPerBlock;
  dim3 grid(KOFF * blocksPerK);
  spconv_mfma_kernel<ITER><<<grid, 256, 0, stream>>>(feat, kern, nin, nout, out,
                                                     Lpairs, blocksPerK);
}

// Round 2
// 268.030 us; speedup vs baseline: 1.0902x; 1.0902x over previous
//
#include <hip/hip_runtime.h>
#include <hip/hip_bf16.h>

// Sparse conv gather->GEMM->scatter for MI355X (gfx950), 3-phase (no f32 atomics):
//   K1: histogram neighbor_out + slot table (CSR-lite, cap 64/row)
//   K2: per-offset MFMA GEMM -> vals[pair][64ch] bf16 in ws (transposed mfma)
//   K3: per-row segmented reduce over slot list -> out (single write per row)
// Fallback to the atomic kernel if ws_size is insufficient.

typedef __bf16 bf16x8 __attribute__((ext_vector_type(8)));
typedef __bf16 bf16x4 __attribute__((ext_vector_type(4)));
typedef float f32x4 __attribute__((ext_vector_type(4)));

#define KOFF 27
#define CAP 64

// ---- K1: histogram + slot assignment ----
__global__ __launch_bounds__(256) void k1_hist(const int* __restrict__ nout,
                                               int* __restrict__ counts,
                                               int* __restrict__ slots, int total) {
  int p = blockIdx.x * 256 + threadIdx.x;
  if (p >= total) return;
  int r = nout[p];
  int rank = atomicAdd(&counts[r], 1);
  if (rank < CAP) slots[r * CAP + rank] = p;
}

// ---- K2: per-offset GEMM, vals (bf16) to ws, no atomics ----
// Swapped-operand mfma: D[ch][pair]; lane (g,r) owns pair base+r, channels t*16+g*4+{0..3}.
template <int ITER>
__global__ __launch_bounds__(256) void k2_gemm(const float* __restrict__ feat,
                                               const float* __restrict__ kern,
                                               const int* __restrict__ nin,
                                               __bf16* __restrict__ vals,
                                               int Lpairs, int blocksPerK) {
  __shared__ __bf16 ldsBT[64 * 64];  // ldsBT[c][i] = W[i][c]
  const int bk = blockIdx.x / blocksPerK;
  const int chunk = blockIdx.x % blocksPerK;
  const float* kb = kern + bk * 4096;
  for (int idx = threadIdx.x; idx < 4096; idx += 256) {
    int i = idx >> 6, c = idx & 63;
    ldsBT[c * 64 + i] = (__bf16)kb[idx];
  }
  __syncthreads();

  const int lane = threadIdx.x & 63;
  const int wave = threadIdx.x >> 6;
  const int r = lane & 15, g = lane >> 4;

  // W fragment (A operand): A[m=r (ch within tile t)][k=g*8+s*32+j] = ldsBT[(t*16+r)*64 + ...]
  bf16x8 wfrag[2][4];
#pragma unroll
  for (int s = 0; s < 2; ++s)
#pragma unroll
    for (int t = 0; t < 4; ++t)
      wfrag[s][t] = *(const bf16x8*)&ldsBT[(t * 16 + r) * 64 + g * 8 + s * 32];

  const int* ninK = nin + bk * Lpairs;
  const int base0 = chunk * (4 * ITER * 16) + wave * (ITER * 16);

  for (int it = 0; it < ITER; ++it) {
    const int base = base0 + it * 16;
    if (base >= Lpairs) break;  // Lpairs % 16 == 0 -> full tiles

    // feat fragment (B operand): B[k=g*8+s*32+j][n=r] = feat[nin[base+r]][k]
    const int arow = ninK[base + r];
    const float* ap = feat + (size_t)arow * 64 + g * 8;
    f32x4 f0 = *(const f32x4*)(ap);
    f32x4 f1 = *(const f32x4*)(ap + 4);
    f32x4 f2 = *(const f32x4*)(ap + 32);
    f32x4 f3 = *(const f32x4*)(ap + 36);
    bf16x8 a0, a1;
#pragma unroll
    for (int j = 0; j < 4; ++j) {
      a0[j] = (__bf16)f0[j];
      a0[j + 4] = (__bf16)f1[j];
      a1[j] = (__bf16)f2[j];
      a1[j + 4] = (__bf16)f3[j];
    }

    f32x4 acc[4] = {f32x4{0.f, 0.f, 0.f, 0.f}, f32x4{0.f, 0.f, 0.f, 0.f},
                    f32x4{0.f, 0.f, 0.f, 0.f}, f32x4{0.f, 0.f, 0.f, 0.f}};
#pragma unroll
    for (int t = 0; t < 4; ++t) {
      acc[t] = __builtin_amdgcn_mfma_f32_16x16x32_bf16(wfrag[0][t], a0, acc[t], 0, 0, 0);
      acc[t] = __builtin_amdgcn_mfma_f32_16x16x32_bf16(wfrag[1][t], a1, acc[t], 0, 0, 0);
    }

    // D layout: col=lane&15 -> pair r, row=g*4+reg -> channel t*16+g*4+reg
    __bf16* vp = vals + ((size_t)bk * Lpairs + base + r) * 64;
#pragma unroll
    for (int t = 0; t < 4; ++t) {
      bf16x4 v;
#pragma unroll
      for (int reg = 0; reg < 4; ++reg) v[reg] = (__bf16)acc[t][reg];
      *(bf16x4*)(vp + t * 16 + g * 4) = v;  // 8B store
    }
  }
}

// ---- K3: per-row segmented reduce ----
__global__ __launch_bounds__(256) void k3_reduce(const __bf16* __restrict__ vals,
                                                 const int* __restrict__ counts,
                                                 const int* __restrict__ slots,
                                                 float* __restrict__ out, int Nrows) {
  const int wid = (blockIdx.x * 256 + threadIdx.x) >> 6;
  const int lane = threadIdx.x & 63;
  if (wid >= Nrows) return;
  int cnt = counts[wid];
  cnt = cnt > CAP ? CAP : cnt;
  int myslot = (lane < cnt) ? slots[wid * CAP + lane] : 0;
  float acc = 0.f;
  int j = 0;
  for (; j + 1 < cnt; j += 2) {
    int s0 = __shfl(myslot, j);
    int s1 = __shfl(myslot, j + 1);
    float v0 = (float)vals[(size_t)s0 * 64 + lane];
    float v1 = (float)vals[(size_t)s1 * 64 + lane];
    acc += v0;
    acc += v1;
  }
  if (j < cnt) {
    int s0 = __shfl(myslot, j);
    acc += (float)vals[(size_t)s0 * 64 + lane];
  }
  out[(size_t)wid * 64 + lane] = acc;
}

// ---- Fallback: round-1 atomic kernel (used only if ws too small) ----
template <int ITER>
__global__ __launch_bounds__(256) void spconv_atomic_kernel(
    const float* __restrict__ feat, const float* __restrict__ kern,
    const int* __restrict__ nin, const int* __restrict__ nout,
    float* __restrict__ out, int Lpairs, int blocksPerK) {
  __shared__ __bf16 ldsBT[64 * 64];
  const int bk = blockIdx.x / blocksPerK;
  const int chunk = blockIdx.x % blocksPerK;
  const float* kb = kern + bk * 4096;
  for (int idx = threadIdx.x; idx < 4096; idx += 256) {
    int i = idx >> 6, c = idx & 63;
    ldsBT[c * 64 + i] = (__bf16)kb[idx];
  }
  __syncthreads();
  const int lane = threadIdx.x & 63;
  const int wave = threadIdx.x >> 6;
  const int r = lane & 15, g = lane >> 4;
  bf16x8 bfrag[2][4];
#pragma unroll
  for (int s = 0; s < 2; ++s)
#pragma unroll
    for (int t = 0; t < 4; ++t)
      bfrag[s][t] = *(const bf16x8*)&ldsBT[(t * 16 + r) * 64 + g * 8 + s * 32];
  const int* ninK = nin + bk * Lpairs;
  const int* noutK = nout + bk * Lpairs;
  const int base0 = chunk * (4 * ITER * 16) + wave * (ITER * 16);
  for (int it = 0; it < ITER; ++it) {
    const int base = base0 + it * 16;
    if (base >= Lpairs) break;
    const int arow = ninK[base + r];
    const float* ap = feat + (size_t)arow * 64 + g * 8;
    f32x4 f0 = *(const f32x4*)(ap);
    f32x4 f1 = *(const f32x4*)(ap + 4);
    f32x4 f2 = *(const f32x4*)(ap + 32);
    f32x4 f3 = *(const f32x4*)(ap + 36);
    bf16x8 a0, a1;
#pragma unroll
    for (int j = 0; j < 4; ++j) {
      a0[j] = (__bf16)f0[j];
      a0[j + 4] = (__bf16)f1[j];
      a1[j] = (__bf16)f2[j];
      a1[j + 4] = (__bf16)f3[j];
    }
    f32x4 acc[4] = {f32x4{0.f, 0.f, 0.f, 0.f}, f32x4{0.f, 0.f, 0.f, 0.f},
                    f32x4{0.f, 0.f, 0.f, 0.f}, f32x4{0.f, 0.f, 0.f, 0.f}};
#pragma unroll
    for (int t = 0; t < 4; ++t) {
      acc[t] = __builtin_amdgcn_mfma_f32_16x16x32_bf16(a0, bfrag[0][t], acc[t], 0, 0, 0);
      acc[t] = __builtin_amdgcn_mfma_f32_16x16x32_bf16(a1, bfrag[1][t], acc[t], 0, 0, 0);
    }
    int orow[4];
#pragma unroll
    for (int reg = 0; reg < 4; ++reg) orow[reg] = noutK[base + g * 4 + reg];
#pragma unroll
    for (int t = 0; t < 4; ++t)
#pragma unroll
      for (int reg = 0; reg < 4; ++reg)
        atomicAdd(out + (size_t)orow[reg] * 64 + t * 16 + r, acc[t][reg]);
  }
}

extern "C" void kernel_launch(void* const* d_in, const int* in_sizes, int n_in,
                              void* d_out, int out_size, void* d_ws, size_t ws_size,
                              hipStream_t stream) {
  const float* feat = (const float*)d_in[0];
  const float* kern = (const float*)d_in[1];
  const int* nin = (const int*)d_in[2];
  const int* nout = (const int*)d_in[3];
  float* out = (float*)d_out;

  const int total = in_sizes[2];        // 27*L pairs
  const int Lpairs = total / KOFF;      // 50000
  const int Nrows = out_size / 64;      // 100000

  constexpr int ITER = 8;
  const int pairsPerBlock = 4 * ITER * 16;  // 512
  const int blocksPerK = (Lpairs + pairsPerBlock - 1) / pairsPerBlock;

  // ws layout
  const size_t countsOff = 0;
  const size_t slotsOff = (((size_t)Nrows * 4) + 255) & ~(size_t)255;
  const size_t valsOff = ((slotsOff + (size_t)Nrows * CAP * 4) + 255) & ~(size_t)255;
  const size_t needed = valsOff + (size_t)total * 64 * 2;

  if (ws_size >= needed) {
    int* counts = (int*)((char*)d_ws + countsOff);
    int* slots = (int*)((char*)d_ws + slotsOff);
    __bf16* vals = (__bf16*)((char*)d_ws + valsOff);

    hipMemsetAsync(counts, 0, (size_t)Nrows * 4, stream);
    k1_hist<<<(total + 255) / 256, 256, 0, stream>>>(nout, counts, slots, total);
    k2_gemm<ITER><<<KOFF * blocksPerK, 256, 0, stream>>>(feat, kern, nin, vals,
                                                         Lpairs, blocksPerK);
    k3_reduce<<<(Nrows * 64 + 255) / 256, 256, 0, stream>>>(vals, counts, slots,
                                                            out, Nrows);
  } else {
    hipMemsetAsync(d_out, 0, (size_t)out_size * sizeof(float), stream);
    spconv_atomic_kernel<ITER><<<KOFF * blocksPerK, 256, 0, stream>>>(
        feat, kern, nin, nout, out, Lpairs, blocksPerK);
  }
}

// Round 3
// 184.188 us; speedup vs baseline: 1.5864x; 1.4552x over previous
//
#include <hip/hip_runtime.h>
#include <hip/hip_bf16.h>

// Sparse conv gather->GEMM->scatter for MI355X (gfx950), 2-phase:
//   K2': per-offset MFMA GEMM -> vals[pair][64ch] bf16 in ws
//        + fused histogram/slot-table build (hides atomic latency under MFMA)
//   K3 : per-row segmented reduce over slot list -> out (single write per row)
// Fallback to a pure-atomic kernel if ws_size is insufficient.

typedef __bf16 bf16x8 __attribute__((ext_vector_type(8)));
typedef __bf16 bf16x4 __attribute__((ext_vector_type(4)));
typedef float f32x4 __attribute__((ext_vector_type(4)));

#define KOFF 27
#define CAP 64

// ---- K2': per-offset GEMM + fused hist, vals (bf16) to ws ----
// Swapped-operand mfma: D[ch][pair]; lane (g,r) owns pair base+r, channels t*16+g*4+{0..3}.
template <int ITER>
__global__ __launch_bounds__(256) void k2_gemm_hist(
    const float* __restrict__ feat, const float* __restrict__ kern,
    const int* __restrict__ nin, const int* __restrict__ nout,
    int* __restrict__ counts, int* __restrict__ slots,
    __bf16* __restrict__ vals, int Lpairs, int blocksPerK) {
  __shared__ __bf16 ldsBT[64 * 64];  // ldsBT[c][i] = W[i][c]
  const int bk = blockIdx.x / blocksPerK;
  const int chunk = blockIdx.x % blocksPerK;
  const float* kb = kern + bk * 4096;
  for (int idx = threadIdx.x; idx < 4096; idx += 256) {
    int i = idx >> 6, c = idx & 63;
    ldsBT[c * 64 + i] = (__bf16)kb[idx];
  }
  __syncthreads();

  const int lane = threadIdx.x & 63;
  const int wave = threadIdx.x >> 6;
  const int r = lane & 15, g = lane >> 4;

  // W fragment (A operand): A[m=r][k=g*8+s*32+j] = ldsBT[(t*16+r)*64 + ...]
  bf16x8 wfrag[2][4];
#pragma unroll
  for (int s = 0; s < 2; ++s)
#pragma unroll
    for (int t = 0; t < 4; ++t)
      wfrag[s][t] = *(const bf16x8*)&ldsBT[(t * 16 + r) * 64 + g * 8 + s * 32];

  const int* ninK = nin + bk * Lpairs;
  const int* noutK = nout + bk * Lpairs;
  const int base0 = chunk * (4 * ITER * 16) + wave * (ITER * 16);

  // Fused histogram + slot assignment for this wave's ITER*16 pairs.
  // Lanes g==0 (r = 0..15) each own pair (base + r) of every tile.
  // All 8 atomics issued independently -> latency overlaps the MFMA loop below.
  if (g == 0) {
    int rows[ITER];
#pragma unroll
    for (int it = 0; it < ITER; ++it) {
      int base = base0 + it * 16;
      rows[it] = (base < Lpairs) ? noutK[base + r] : -1;
    }
#pragma unroll
    for (int it = 0; it < ITER; ++it) {
      if (rows[it] >= 0) {
        int rank = atomicAdd(&counts[rows[it]], 1);
        if (rank < CAP)
          slots[rows[it] * CAP + rank] = bk * Lpairs + base0 + it * 16 + r;
      }
    }
  }

  for (int it = 0; it < ITER; ++it) {
    const int base = base0 + it * 16;
    if (base >= Lpairs) break;  // Lpairs % 16 == 0 -> full tiles

    // feat fragment (B operand): B[k=g*8+s*32+j][n=r] = feat[nin[base+r]][k]
    const int arow = ninK[base + r];
    const float* ap = feat + (size_t)arow * 64 + g * 8;
    f32x4 f0 = *(const f32x4*)(ap);
    f32x4 f1 = *(const f32x4*)(ap + 4);
    f32x4 f2 = *(const f32x4*)(ap + 32);
    f32x4 f3 = *(const f32x4*)(ap + 36);
    bf16x8 a0, a1;
#pragma unroll
    for (int j = 0; j < 4; ++j) {
      a0[j] = (__bf16)f0[j];
      a0[j + 4] = (__bf16)f1[j];
      a1[j] = (__bf16)f2[j];
      a1[j + 4] = (__bf16)f3[j];
    }

    f32x4 acc[4] = {f32x4{0.f, 0.f, 0.f, 0.f}, f32x4{0.f, 0.f, 0.f, 0.f},
                    f32x4{0.f, 0.f, 0.f, 0.f}, f32x4{0.f, 0.f, 0.f, 0.f}};
#pragma unroll
    for (int t = 0; t < 4; ++t) {
      acc[t] = __builtin_amdgcn_mfma_f32_16x16x32_bf16(wfrag[0][t], a0, acc[t], 0, 0, 0);
      acc[t] = __builtin_amdgcn_mfma_f32_16x16x32_bf16(wfrag[1][t], a1, acc[t], 0, 0, 0);
    }

    // D layout: col=lane&15 -> pair r, row=g*4+reg -> channel t*16+g*4+reg
    __bf16* vp = vals + ((size_t)bk * Lpairs + base + r) * 64;
#pragma unroll
    for (int t = 0; t < 4; ++t) {
      bf16x4 v;
#pragma unroll
      for (int reg = 0; reg < 4; ++reg) v[reg] = (__bf16)acc[t][reg];
      *(bf16x4*)(vp + t * 16 + g * 4) = v;  // 8B store
    }
  }
}

// ---- K3: per-row segmented reduce, 4-deep ILP ----
__global__ __launch_bounds__(256) void k3_reduce(const __bf16* __restrict__ vals,
                                                 const int* __restrict__ counts,
                                                 const int* __restrict__ slots,
                                                 float* __restrict__ out, int Nrows) {
  const int wid = (blockIdx.x * 256 + threadIdx.x) >> 6;
  const int lane = threadIdx.x & 63;
  if (wid >= Nrows) return;
  int cnt = counts[wid];
  cnt = cnt > CAP ? CAP : cnt;
  int myslot = (lane < cnt) ? slots[wid * CAP + lane] : 0;
  float acc = 0.f;
  int j = 0;
  for (; j + 3 < cnt; j += 4) {
    int s0 = __shfl(myslot, j);
    int s1 = __shfl(myslot, j + 1);
    int s2 = __shfl(myslot, j + 2);
    int s3 = __shfl(myslot, j + 3);
    float v0 = (float)vals[(size_t)s0 * 64 + lane];
    float v1 = (float)vals[(size_t)s1 * 64 + lane];
    float v2 = (float)vals[(size_t)s2 * 64 + lane];
    float v3 = (float)vals[(size_t)s3 * 64 + lane];
    acc += v0;
    acc += v1;
    acc += v2;
    acc += v3;
  }
  for (; j < cnt; ++j) {
    int s0 = __shfl(myslot, j);
    acc += (float)vals[(size_t)s0 * 64 + lane];
  }
  out[(size_t)wid * 64 + lane] = acc;
}

// ---- Fallback: atomic kernel (used only if ws too small) ----
template <int ITER>
__global__ __launch_bounds__(256) void spconv_atomic_kernel(
    const float* __restrict__ feat, const float* __restrict__ kern,
    const int* __restrict__ nin, const int* __restrict__ nout,
    float* __restrict__ out, int Lpairs, int blocksPerK) {
  __shared__ __bf16 ldsBT[64 * 64];
  const int bk = blockIdx.x / blocksPerK;
  const int chunk = blockIdx.x % blocksPerK;
  const float* kb = kern + bk * 4096;
  for (int idx = threadIdx.x; idx < 4096; idx += 256) {
    int i = idx >> 6, c = idx & 63;
    ldsBT[c * 64 + i] = (__bf16)kb[idx];
  }
  __syncthreads();
  const int lane = threadIdx.x & 63;
  const int wave = threadIdx.x >> 6;
  const int r = lane & 15, g = lane >> 4;
  bf16x8 bfrag[2][4];
#pragma unroll
  for (int s = 0; s < 2; ++s)
#pragma unroll
    for (int t = 0; t < 4; ++t)
      bfrag[s][t] = *(const bf16x8*)&ldsBT[(t * 16 + r) * 64 + g * 8 + s * 32];
  const int* ninK = nin + bk * Lpairs;
  const int* noutK = nout + bk * Lpairs;
  const int base0 = chunk * (4 * ITER * 16) + wave * (ITER * 16);
  for (int it = 0; it < ITER; ++it) {
    const int base = base0 + it * 16;
    if (base >= Lpairs) break;
    const int arow = ninK[base + r];
    const float* ap = feat + (size_t)arow * 64 + g * 8;
    f32x4 f0 = *(const f32x4*)(ap);
    f32x4 f1 = *(const f32x4*)(ap + 4);
    f32x4 f2 = *(const f32x4*)(ap + 32);
    f32x4 f3 = *(const f32x4*)(ap + 36);
    bf16x8 a0, a1;
#pragma unroll
    for (int j = 0; j < 4; ++j) {
      a0[j] = (__bf16)f0[j];
      a0[j + 4] = (__bf16)f1[j];
      a1[j] = (__bf16)f2[j];
      a1[j + 4] = (__bf16)f3[j];
    }
    f32x4 acc[4] = {f32x4{0.f, 0.f, 0.f, 0.f}, f32x4{0.f, 0.f, 0.f, 0.f},
                    f32x4{0.f, 0.f, 0.f, 0.f}, f32x4{0.f, 0.f, 0.f, 0.f}};
#pragma unroll
    for (int t = 0; t < 4; ++t) {
      acc[t] = __builtin_amdgcn_mfma_f32_16x16x32_bf16(a0, bfrag[0][t], acc[t], 0, 0, 0);
      acc[t] = __builtin_amdgcn_mfma_f32_16x16x32_bf16(a1, bfrag[1][t], acc[t], 0, 0, 0);
    }
    int orow[4];
#pragma unroll
    for (int reg = 0; reg < 4; ++reg) orow[reg] = noutK[base + g * 4 + reg];
#pragma unroll
    for (int t = 0; t < 4; ++t)
#pragma unroll
      for (int reg = 0; reg < 4; ++reg)
        atomicAdd(out + (size_t)orow[reg] * 64 + t * 16 + r, acc[t][reg]);
  }
}

extern "C" void kernel_launch(void* const* d_in, const int* in_sizes, int n_in,
                              void* d_out, int out_size, void* d_ws, size_t ws_size,
                              hipStream_t stream) {
  const float* feat = (const float*)d_in[0];
  const float* kern = (const float*)d_in[1];
  const int* nin = (const int*)d_in[2];
  const int* nout = (const int*)d_in[3];
  float* out = (float*)d_out;

  const int total = in_sizes[2];        // 27*L pairs
  const int Lpairs = total / KOFF;      // 50000
  const int Nrows = out_size / 64;      // 100000

  constexpr int ITER = 8;
  const int pairsPerBlock = 4 * ITER * 16;  // 512
  const int blocksPerK = (Lpairs + pairsPerBlock - 1) / pairsPerBlock;

  // ws layout
  const size_t countsOff = 0;
  const size_t slotsOff = (((size_t)Nrows * 4) + 255) & ~(size_t)255;
  const size_t valsOff = ((slotsOff + (size_t)Nrows * CAP * 4) + 255) & ~(size_t)255;
  const size_t needed = valsOff + (size_t)total * 64 * 2;

  if (ws_size >= needed) {
    int* counts = (int*)((char*)d_ws + countsOff);
    int* slots = (int*)((char*)d_ws + slotsOff);
    __bf16* vals = (__bf16*)((char*)d_ws + valsOff);

    hipMemsetAsync(counts, 0, (size_t)Nrows * 4, stream);
    k2_gemm_hist<ITER><<<KOFF * blocksPerK, 256, 0, stream>>>(
        feat, kern, nin, nout, counts, slots, vals, Lpairs, blocksPerK);
    k3_reduce<<<(Nrows * 64 + 255) / 256, 256, 0, stream>>>(vals, counts, slots,
                                                            out, Nrows);
  } else {
    hipMemsetAsync(d_out, 0, (size_t)out_size * sizeof(float), stream);
    spconv_atomic_kernel<ITER><<<KOFF * blocksPerK, 256, 0, stream>>>(
        feat, kern, nin, nout, out, Lpairs, blocksPerK);
  }
}